// Round 4
// baseline (908.035 us; speedup 1.0000x reference)
//
#include <hip/hip_runtime.h>
#include <hip/hip_bf16.h>

// Fused LIF layer: per block, W-chunk lives in REGISTERS for the whole kernel;
// x[b,t,:] is staged to LDS each t (double-buffered, prefetch dist 2); the
// GEMV for step t and the scan update happen in-line, so Wx never touches HBM.
//
// Decomposition: 512 blocks = 64 b x 8 h-chunks(64 h). 256 threads = 4 waves.
// Lane (within wave): islice = lane&7 (I-slice of 64 floats),
//                     grp    = lane>>3 (h-group) -> 2 h per lane (R=2).
// Wave covers 16 h; block covers 64 h. Each lane: W[2][64] floats = 128 VGPR.
// Per t: 16 ds_read_b128 (8-way broadcast, slices padded to stride 68 floats
// = disjoint 4-bank groups -> conflict-free) + 64 v_pk_fma_f32, then
// shfl_xor(1,2,4) reduce across islices, scan update in regs, islice0 stores.
// b = blockIdx%64 -> all 8 blocks of one b land on one XCD (L2 x-reuse).
//
// fp32 end-to-end: binary output tolerates no spike flips; R0-R2 verified
// absmax == 0.0 under several fp32 accumulation orders.

#define ALPHA_LO_F ((float)0.8187307530779818)   // exp(-1/5)
#define ALPHA_HI_F ((float)0.9607894391523232)   // exp(-1/25)

typedef float v2f __attribute__((ext_vector_type(2)));

#define I_DIM 512
#define H_DIM 512
#define HC    64     // h per block
#define SL    8      // I-slices
#define SLF   64     // floats per slice
#define PADS  68     // LDS slice stride (floats): bank offset 4 per slice

__global__ __launch_bounds__(256, 2) void lif_fused(
    const float* __restrict__ x,      // [B, T, I]
    const float* __restrict__ W,      // [H, I]
    const float* __restrict__ alpha,  // [H]
    const float* __restrict__ u0,     // [B, H]
    const float* __restrict__ s0,     // [B, H]
    float* __restrict__ out,          // [B, T, H]
    int T)
{
    __shared__ float xbuf[2][SL * PADS];   // 2 x 544 floats = 4352 B

    const int tid  = threadIdx.x;
    const int b    = blockIdx.x & 63;      // same-b blocks differ by 64 -> same XCD (%8)
    const int hc   = blockIdx.x >> 6;      // 0..7
    const int lane = tid & 63;
    const int wave = tid >> 6;
    const int isl  = lane & 7;
    const int grp  = lane >> 3;
    const int h0   = hc * HC + wave * 16 + grp * 2;   // this lane's two h rows

    // ---- W fragments -> registers (held for entire kernel) ----
    v2f wreg[2][32];
    #pragma unroll
    for (int r = 0; r < 2; ++r) {
        const float* Wrow = W + (size_t)(h0 + r) * I_DIM + isl * SLF;
        #pragma unroll
        for (int j = 0; j < 16; ++j) {
            float4 v = *(const float4*)(Wrow + j * 4);
            wreg[r][2 * j]     = (v2f){v.x, v.y};
            wreg[r][2 * j + 1] = (v2f){v.z, v.w};
        }
    }

    // ---- scan state (redundant across the 8 islice lanes; only isl==0 stores)
    float u[2], s[2], al[2], oma[2];
    #pragma unroll
    for (int r = 0; r < 2; ++r) {
        const int h = h0 + r;
        float a = alpha[h];
        a = fminf(fmaxf(a, ALPHA_LO_F), ALPHA_HI_F);
        al[r] = a; oma[r] = 1.0f - a;
        u[r] = u0[(size_t)b * H_DIM + h];
        s[r] = s0[(size_t)b * H_DIM + h];
    }

    // ---- x staging map: each thread writes 2 floats (f = tid*2) ----
    const int f    = tid * 2;
    const int wofs = (f >> 6) * PADS + (f & 63);
    const float* xb = x + (size_t)b * T * I_DIM;

    float2 pf[2];
    pf[0] = *(const float2*)(xb + f);                                  // x(0)
    pf[1] = *(const float2*)(xb + (size_t)(T > 1 ? 1 : 0) * I_DIM + f); // x(1)
    xbuf[0][wofs]     = pf[0].x;
    xbuf[0][wofs + 1] = pf[0].y;
    __syncthreads();

    const int rbase = isl * PADS;
    size_t outIdx = (size_t)b * T * H_DIM + h0;

    for (int t = 0; t < T; ++t) {
        // prefetch x(t+2) into the slot freed last iteration
        const int tl = (t + 2 < T) ? (t + 2) : (T - 1);
        pf[t & 1] = *(const float2*)(xb + (size_t)tl * I_DIM + f);

        // GEMV slice: dot(W[h0+r][isl*64..+64), x[t][isl*64..+64))
        const float* xs = &xbuf[t & 1][rbase];
        v2f a00 = (v2f){0.f, 0.f}, a01 = (v2f){0.f, 0.f};
        v2f a10 = (v2f){0.f, 0.f}, a11 = (v2f){0.f, 0.f};
        #pragma unroll
        for (int j = 0; j < 16; ++j) {
            float4 xv = *(const float4*)(xs + j * 4);   // 8-way broadcast, conflict-free
            v2f xlo = (v2f){xv.x, xv.y};
            v2f xhi = (v2f){xv.z, xv.w};
            a00 = __builtin_elementwise_fma(wreg[0][2 * j],     xlo, a00);
            a01 = __builtin_elementwise_fma(wreg[0][2 * j + 1], xhi, a01);
            a10 = __builtin_elementwise_fma(wreg[1][2 * j],     xlo, a10);
            a11 = __builtin_elementwise_fma(wreg[1][2 * j + 1], xhi, a11);
        }
        float dot0, dot1;
        { v2f a = a00 + a01; dot0 = a.x + a.y; }
        { v2f a = a10 + a11; dot1 = a.x + a.y; }
        // reduce across the 8 islice lanes (bits 0..2 of lane)
        #pragma unroll
        for (int m = 1; m <= 4; m <<= 1) {
            dot0 += __shfl_xor(dot0, m, 64);
            dot1 += __shfl_xor(dot1, m, 64);
        }

        // scan update (identical on all 8 islice lanes)
        u[0] = al[0] * (u[0] - s[0]) + oma[0] * dot0;
        s[0] = (u[0] - 1.0f > 0.0f) ? 1.0f : 0.0f;
        u[1] = al[1] * (u[1] - s[1]) + oma[1] * dot1;
        s[1] = (u[1] - 1.0f > 0.0f) ? 1.0f : 0.0f;

        if (isl == 0) {
            *(float2*)(out + outIdx) = make_float2(s[0], s[1]);
        }
        outIdx += H_DIM;

        // stage x(t+1) into the other LDS buffer; one barrier per t
        const float2 nx = pf[(t + 1) & 1];
        xbuf[(t + 1) & 1][wofs]     = nx.x;
        xbuf[(t + 1) & 1][wofs + 1] = nx.y;
        __syncthreads();
    }
}

extern "C" void kernel_launch(void* const* d_in, const int* in_sizes, int n_in,
                              void* d_out, int out_size, void* d_ws, size_t ws_size,
                              hipStream_t stream) {
    const float* x     = (const float*)d_in[0];   // [B, T, I]
    const float* W     = (const float*)d_in[1];   // [H, I]
    const float* alpha = (const float*)d_in[2];   // [H]
    const float* u0    = (const float*)d_in[3];   // [B, H]
    const float* s0    = (const float*)d_in[4];   // [B, H]
    float* out = (float*)d_out;                   // [B, T, H]

    const int H = in_sizes[2];                    // 512 (structure assumes this)
    const int B = in_sizes[3] / H;                // 64
    const int T = in_sizes[0] / (B * I_DIM);      // 1024

    const int grid = B * (H_DIM / HC);            // 64 * 8 = 512 blocks
    lif_fused<<<grid, 256, 0, stream>>>(x, W, alpha, u0, s0, out, T);
}

// Round 5
// 726.013 us; speedup vs baseline: 1.2507x; 1.2507x over previous
//
#include <hip/hip_runtime.h>
#include <hip/hip_bf16.h>

// Fused LIF: per block = (one b) x (128-h chunk). Loop over 4 time-chunks of
// 256 t: R2-proven fp32 tile GEMM (256t x 128h x 512K, BK=16, 8x8 frag/thread,
// v_pk_fma_f32) with C in registers, then in-block scan of those 256 steps via
// LDS-carried (u,s), 32 pipelined stages. Wx never touches HBM; no separate
// scan kernel. Accumulation order per (t,h) identical to R2 -> bit-identical
// Wx -> absmax 0 expected (binary output tolerates no flips).
//
// grid = hc*64 + b: the 4 blocks sharing b are 64 apart -> same XCD (%8) ->
// x[b] fetched into that XCD's L2 once, 4x reuse.

#define ALPHA_LO_F 0.8187307530779818f   // exp(-1/5)
#define ALPHA_HI_F 0.9607894391523232f   // exp(-1/25)

typedef float v2f __attribute__((ext_vector_type(2)));

#define T_DIM 1024
#define K_DIM 512
#define H_DIM 512
#define CT    256        // t-rows per chunk
#define CH    128        // h per block
#define NCHK  (T_DIM / CT)
#define BK    16
#define APAD  260        // As row stride (floats): 4-float pad -> scatter writes 2-way max
#define BPAD  132        // Bs row stride

__global__ __launch_bounds__(512, 1) void lif_fused(
    const float* __restrict__ x,      // [B, T, K]
    const float* __restrict__ W,      // [H, K]
    const float* __restrict__ alpha,  // [H]
    const float* __restrict__ u0,     // [B, H]
    const float* __restrict__ s0,     // [B, H]
    float* __restrict__ out)          // [B, T, H]
{
    __shared__ float As[BK][APAD];    // x tile, transposed: As[k][t-row]
    __shared__ float Bs[BK][BPAD];    // W tile: Bs[k][h-col]
    __shared__ float u_s[CH], s_s[CH], al_s[CH];

    const int tid = threadIdx.x;
    const int b   = blockIdx.x & 63;
    const int hc  = blockIdx.x >> 6;      // 0..3
    const int h0  = hc * CH;

    // ---- init per-h scan state (held in LDS for the whole kernel) ----
    if (tid < CH) {
        const int h = h0 + tid;
        float a = alpha[h];
        al_s[tid] = fminf(fmaxf(a, ALPHA_LO_F), ALPHA_HI_F);
        u_s[tid] = u0[(size_t)b * H_DIM + h];
        s_s[tid] = s0[(size_t)b * H_DIM + h];
    }

    const int tm = tid >> 4;              // 0..31 : t-row group (8 rows)
    const int tn = tid & 15;              // 0..15 : h-col group (8 cols)

    const float* xb = x + (size_t)b * T_DIM * K_DIM;
    const float* Wc = W + (size_t)h0 * K_DIM;

    __syncthreads();

    for (int c = 0; c < NCHK; ++c) {
        const int t0 = c * CT;

        // ================= GEMM phase: C[256t][128h] in regs =================
        v2f acc[8][4] = {};

        for (int k0 = 0; k0 < K_DIM; k0 += BK) {
            // stage tiles: 1024 float4 of A + 512 float4 of B over 512 threads
            #pragma unroll
            for (int r = 0; r < 3; ++r) {
                const int fid = tid + r * 512;
                if (fid < 1024) {
                    const int row = fid >> 2;
                    const int kq  = (fid & 3) * 4;
                    float4 v = *(const float4*)(xb + (size_t)(t0 + row) * K_DIM + k0 + kq);
                    As[kq + 0][row] = v.x;  As[kq + 1][row] = v.y;
                    As[kq + 2][row] = v.z;  As[kq + 3][row] = v.w;
                } else {
                    const int g   = fid - 1024;
                    const int row = g >> 2;
                    const int kq  = (g & 3) * 4;
                    float4 v = *(const float4*)(Wc + (size_t)row * K_DIM + k0 + kq);
                    Bs[kq + 0][row] = v.x;  Bs[kq + 1][row] = v.y;
                    Bs[kq + 2][row] = v.z;  Bs[kq + 3][row] = v.w;
                }
            }
            __syncthreads();

            #pragma unroll
            for (int k = 0; k < BK; ++k) {
                const float* Ak = &As[k][tm * 8];
                const float* Bk = &Bs[k][tn * 8];
                float4 a0 = *(const float4*)(Ak);
                float4 a1 = *(const float4*)(Ak + 4);
                float4 b0 = *(const float4*)(Bk);
                float4 b1 = *(const float4*)(Bk + 4);
                v2f bb[4];
                bb[0] = (v2f){b0.x, b0.y};  bb[1] = (v2f){b0.z, b0.w};
                bb[2] = (v2f){b1.x, b1.y};  bb[3] = (v2f){b1.z, b1.w};
                float a[8] = {a0.x, a0.y, a0.z, a0.w, a1.x, a1.y, a1.z, a1.w};
                #pragma unroll
                for (int i = 0; i < 8; ++i) {
                    v2f ai = (v2f){a[i], a[i]};
                    #pragma unroll
                    for (int jv = 0; jv < 4; ++jv)
                        acc[i][jv] = __builtin_elementwise_fma(ai, bb[jv], acc[i][jv]);
                }
            }
            __syncthreads();
        }

        // ================= scan phase: 32 sequential stages =================
        // stage k: threads with tm==k advance t-rows 8k..8k+7 for their 8 h.
        for (int stage = 0; stage < 32; ++stage) {
            if (tm == stage) {
                const int hb = tn * 8;
                float u[8], s[8], av[8], om[8];
                #pragma unroll
                for (int j = 0; j < 8; ++j) {
                    u[j]  = u_s[hb + j];
                    s[j]  = s_s[hb + j];
                    av[j] = al_s[hb + j];
                    om[j] = 1.0f - av[j];
                }
                #pragma unroll
                for (int i = 0; i < 8; ++i) {
                    float wx[8] = {acc[i][0].x, acc[i][0].y, acc[i][1].x, acc[i][1].y,
                                   acc[i][2].x, acc[i][2].y, acc[i][3].x, acc[i][3].y};
                    #pragma unroll
                    for (int j = 0; j < 8; ++j) {
                        u[j] = av[j] * (u[j] - s[j]) + om[j] * wx[j];
                        s[j] = (u[j] - 1.0f > 0.0f) ? 1.0f : 0.0f;
                    }
                    const int t = t0 + stage * 8 + i;
                    float* orow = out + ((size_t)b * T_DIM + t) * H_DIM + h0 + hb;
                    *(float4*)(orow)     = make_float4(s[0], s[1], s[2], s[3]);
                    *(float4*)(orow + 4) = make_float4(s[4], s[5], s[6], s[7]);
                }
                #pragma unroll
                for (int j = 0; j < 8; ++j) {
                    u_s[hb + j] = u[j];
                    s_s[hb + j] = s[j];
                }
            }
            __syncthreads();
        }
    }
}

extern "C" void kernel_launch(void* const* d_in, const int* in_sizes, int n_in,
                              void* d_out, int out_size, void* d_ws, size_t ws_size,
                              hipStream_t stream) {
    const float* x     = (const float*)d_in[0];   // [B, T, I]
    const float* W     = (const float*)d_in[1];   // [H, I]
    const float* alpha = (const float*)d_in[2];   // [H]
    const float* u0    = (const float*)d_in[3];   // [B, H]
    const float* s0    = (const float*)d_in[4];   // [B, H]
    float* out = (float*)d_out;                   // [B, T, H]

    const int H = in_sizes[2];                    // 512
    const int B = in_sizes[3] / H;                // 64
    const int grid = (H_DIM / CH) * B;            // 4 * 64 = 256 blocks

    lif_fused<<<grid, 512, 0, stream>>>(x, W, alpha, u0, s0, out);
}